// Round 4
// baseline (285.997 us; speedup 1.0000x reference)
//
#include <hip/hip_runtime.h>

#define N_TOK 32768
#define D 256
#define DFF 1024
#define NE 8
#define TB 128   // tokens per expert_ffn block

typedef __attribute__((ext_vector_type(16))) float f32x16;
typedef __attribute__((ext_vector_type(8)))  short bf16x8;

// fp32 -> bf16 round-to-nearest-even
__device__ __forceinline__ unsigned short f2bf(float f) {
    union { float f; unsigned u; } v; v.f = f;
    unsigned r = v.u + 0x7FFFu + ((v.u >> 16) & 1u);
    return (unsigned short)(r >> 16);
}

// ===========================================================================
// Prepass: w1 [E][D=256 d][DFF=1024 f] fp32 -> frag-major bf16 (GEMM1-A).
// frag = (e*32+fblk)*16 + dblk; element (lane l, j): f = fblk*32 + (l&31),
// d = dblk*16 + (l>>5)*8 + j.  (verified in rounds 2-3)
// ===========================================================================
__global__ __launch_bounds__(256) void w1f_prep(
    const float* __restrict__ w1, short* __restrict__ w1f) {
    const int gid  = blockIdx.x * 256 + threadIdx.x;
    const int lane = gid & 63;
    const int frag = gid >> 6;
    const int dblk = frag & 15;
    const int fblk = (frag >> 4) & 31;
    const int e    = frag >> 9;
    const int l31 = lane & 31, g = lane >> 5;

    const float* src = w1 + ((size_t)e * 256 + dblk * 16 + g * 8) * 1024
                          + fblk * 32 + l31;
    unsigned u[4];
#pragma unroll
    for (int jp = 0; jp < 4; ++jp) {
        float a = src[(size_t)(jp * 2)     * 1024];
        float b = src[(size_t)(jp * 2 + 1) * 1024];
        u[jp] = (unsigned)f2bf(a) | ((unsigned)f2bf(b) << 16);
    }
    *(uint4*)(w1f + (size_t)gid * 8) = make_uint4(u[0], u[1], u[2], u[3]);
}

// ===========================================================================
// Prepass: w2 [E][DFF f][D col] fp32 -> frag-major bf16 (GEMM2-B).
// frag = (e*8+cblk)*64 + fblk; element: col = cblk*32 + (l&31),
// f = fblk*16 + (l>>5)*8 + j.  (verified in rounds 2-3)
// ===========================================================================
__global__ __launch_bounds__(256) void w2f_prep(
    const float* __restrict__ w2, short* __restrict__ w2f) {
    const int gid  = blockIdx.x * 256 + threadIdx.x;
    const int lane = gid & 63;
    const int frag = gid >> 6;
    const int fblk = frag & 63;
    const int cblk = (frag >> 6) & 7;
    const int e    = frag >> 9;
    const int l31 = lane & 31, g = lane >> 5;

    const float* src = w2 + ((size_t)e * 1024 + fblk * 16 + g * 8) * 256
                          + cblk * 32 + l31;
    unsigned u[4];
#pragma unroll
    for (int jp = 0; jp < 4; ++jp) {
        float a = src[(size_t)(jp * 2)     * 256];
        float b = src[(size_t)(jp * 2 + 1) * 256];
        u[jp] = (unsigned)f2bf(a) | ((unsigned)f2bf(b) << 16);
    }
    *(uint4*)(w2f + (size_t)gid * 8) = make_uint4(u[0], u[1], u[2], u[3]);
}

// ===========================================================================
// Gate phase A: per-token fp64 logits + top-2 + softmax; per-block histogram.
// 256 blocks x 128 threads (all CUs busy). No contended global atomics.
// ===========================================================================
__global__ __launch_bounds__(128) void gate_compute(
    const float* __restrict__ x, const float* __restrict__ gw,
    const float* __restrict__ gb,
    unsigned* __restrict__ epair, float* __restrict__ probs,
    int* __restrict__ hists) {
    __shared__ float gws[2048];   // [d][e]
    __shared__ int   hist[NE];
    const int tid = threadIdx.x;
#pragma unroll
    for (int i = 0; i < 4; ++i)
        *(float4*)&gws[i * 512 + tid * 4] = *(const float4*)&gw[i * 512 + tid * 4];
    if (tid < NE) hist[tid] = 0;
    __syncthreads();

    const int t = blockIdx.x * 128 + tid;
    const float* xr = x + (size_t)t * D;

    double acc[NE];
#pragma unroll
    for (int e = 0; e < NE; ++e) acc[e] = 0.0;

    for (int d0 = 0; d0 < 256; d0 += 4) {
        float4 xv = *(const float4*)(xr + d0);
        float xa[4] = {xv.x, xv.y, xv.z, xv.w};
#pragma unroll
        for (int j = 0; j < 4; ++j) {
            float4 ga = *(const float4*)&gws[(d0 + j) * 8];
            float4 gbb = *(const float4*)&gws[(d0 + j) * 8 + 4];
            double xd = (double)xa[j];
            acc[0] += xd * (double)ga.x;  acc[1] += xd * (double)ga.y;
            acc[2] += xd * (double)ga.z;  acc[3] += xd * (double)ga.w;
            acc[4] += xd * (double)gbb.x; acc[5] += xd * (double)gbb.y;
            acc[6] += xd * (double)gbb.z; acc[7] += xd * (double)gbb.w;
        }
    }

    double l[NE];
#pragma unroll
    for (int e = 0; e < NE; ++e) l[e] = acc[e] + (double)gb[e];
    int e1 = 0;
#pragma unroll
    for (int e = 1; e < NE; ++e) if (l[e] > l[e1]) e1 = e;
    int e2 = (e1 == 0) ? 1 : 0;
#pragma unroll
    for (int e = 0; e < NE; ++e) if (e != e1 && l[e] > l[e2]) e2 = e;

    double s = 0.0;
#pragma unroll
    for (int e = 0; e < NE; ++e) s += exp(l[e] - l[e1]);

    atomicAdd(&hist[e1], 1);
    atomicAdd(&hist[e2], 1);
    epair[t] = (unsigned)e1 | ((unsigned)e2 << 8);
    probs[2 * t]     = (float)(1.0 / s);
    probs[2 * t + 1] = (float)(exp(l[e2] - l[e1]) / s);
    __syncthreads();
    if (tid < NE) hists[blockIdx.x * NE + tid] = hist[tid];
}

// ===========================================================================
// Gate phase B: exclusive prefix scan of per-block histograms. 1 block, 256 thr.
// ===========================================================================
__global__ __launch_bounds__(256) void gate_scan(
    const int* __restrict__ hists, int* __restrict__ bases, int* __restrict__ cnt) {
    __shared__ int s[256];
    const int tid = threadIdx.x;
    for (int e = 0; e < NE; ++e) {
        int v = hists[tid * NE + e];
        s[tid] = v;
        __syncthreads();
        for (int off = 1; off < 256; off <<= 1) {
            int t = (tid >= off) ? s[tid - off] : 0;
            __syncthreads();
            s[tid] += t;
            __syncthreads();
        }
        bases[tid * NE + e] = s[tid] - v;
        if (tid == 255) cnt[e] = s[255];
        __syncthreads();
    }
}

// ===========================================================================
// Gate phase C: scatter tokens into per-expert bins at reserved ranges.
// ===========================================================================
__global__ __launch_bounds__(128) void gate_scatter(
    const unsigned* __restrict__ epair, const float* __restrict__ probs,
    const int* __restrict__ bases,
    int* __restrict__ bidx, float* __restrict__ bp) {
    __shared__ int hist[NE], bs[NE];
    const int tid = threadIdx.x;
    if (tid < NE) { hist[tid] = 0; bs[tid] = bases[blockIdx.x * NE + tid]; }
    __syncthreads();
    const int t = blockIdx.x * 128 + tid;
    const unsigned u = epair[t];
    const int e1 = u & 255, e2 = (u >> 8) & 255;
    const float p1 = probs[2 * t], p2 = probs[2 * t + 1];
    const int pos1 = atomicAdd(&hist[e1], 1);
    const int pos2 = atomicAdd(&hist[e2], 1);
    const int o1 = e1 * N_TOK + bs[e1] + pos1;
    const int o2 = e2 * N_TOK + bs[e2] + pos2;
    bidx[o1] = t;  bp[o1] = p1;
    bidx[o2] = t;  bp[o2] = p2;
}

// ===========================================================================
// Expert FFN v4. Block = 128 tokens x 256 out, 8 waves (512 thr), fchunk=64.
// MFMA 32x32x16 bf16, conventions verified in r2-r3.
//  - x frags REGISTER-resident (16 frags/wave, loaded once): zero xs LDS.
//  - GEMM1 roles: wave=(tg 0..3 tok-group, fs 0..1 f-strip). A=w1 global
//    frag-major (8-deep rolling prefetch), B=x regs. hacc split 2-way.
//  - hs frag-major in LDS, double-buffered: element (tok,f') at shorts
//    (f'>>3)*256 + tok*8 + (f'&7); reads = contiguous 1KB b128/wave,
//    writes = contiguous 512B b64/wave -> conflict-free both ways.
//  - GEMM2 roles: wave=(cg 0..3 col-group64, tg2 0..1 tok-half). B=w2 global
//    frags issued BEFORE the barrier (latency under barrier wait).
//  - 1 barrier per fchunk. blockIdx&7=expert -> per-XCD L2 weight affinity.
// ===========================================================================
__global__ __launch_bounds__(512, 2) void expert_ffn(
    const float* __restrict__ x,
    const short* __restrict__ w1f,
    const short* __restrict__ w2f,
    const float* __restrict__ b1, const float* __restrict__ b2,
    const int* __restrict__ cnt, const int* __restrict__ bidx,
    const float* __restrict__ bp, float* __restrict__ out) {
    const int e    = blockIdx.x & 7;
    const int tile = blockIdx.x >> 3;
    const int n_e  = cnt[e];
    const int row0 = tile * TB;
    if (row0 >= n_e) return;

    __shared__ short hs[2][16 * 512];   // 32KB: [buf][frag(fb*4+tg)][512]
    __shared__ int   tok_s[TB];
    __shared__ float p_s[TB];

    const int tid  = threadIdx.x;
    const int lane = tid & 63, wid = tid >> 6;
    const int l31  = lane & 31, g = lane >> 5;
    const int tg = wid & 3, fs = wid >> 2;    // GEMM1 roles
    const int cg = wid & 3, tg2 = wid >> 2;   // GEMM2 roles

    if (tid < TB) {
        int r = row0 + tid;
        tok_s[tid] = (r < n_e) ? bidx[e * N_TOK + r] : -1;
        p_s[tid]   = (r < n_e) ? bp[e * N_TOK + r] : 0.f;
    }
    __syncthreads();

    // ---- x fragments -> registers. xr[db]: element d=db*16+g*8+j, tok=tg*32+l31
    bf16x8 xr[16];
    {
        const int tk = tok_s[tg * 32 + l31];
        const float* xrow = x + (size_t)(tk < 0 ? 0 : tk) * D + g * 8;
#pragma unroll
        for (int db = 0; db < 16; ++db) {
            bf16x8 v;
            if (tk >= 0) {
                float4 a = *(const float4*)(xrow + db * 16);
                float4 b = *(const float4*)(xrow + db * 16 + 4);
                v[0] = (short)f2bf(a.x); v[1] = (short)f2bf(a.y);
                v[2] = (short)f2bf(a.z); v[3] = (short)f2bf(a.w);
                v[4] = (short)f2bf(b.x); v[5] = (short)f2bf(b.y);
                v[6] = (short)f2bf(b.z); v[7] = (short)f2bf(b.w);
            } else {
#pragma unroll
                for (int q = 0; q < 8; ++q) v[q] = 0;
            }
            xr[db] = v;
        }
    }

    f32x16 acc[2][2];   // [tok-half within tg2][col-half]
#pragma unroll
    for (int a = 0; a < 2; ++a)
#pragma unroll
        for (int b = 0; b < 2; ++b)
#pragma unroll
            for (int r = 0; r < 16; ++r) acc[a][b][r] = 0.f;

    const short* w1e = w1f + (size_t)e * (32 * 16 * 512);
    const short* w2e = w2f + (size_t)e * (8 * 64 * 512);
    const float* b1e = b1 + e * DFF;

    for (int fc = 0; fc < 16; ++fc) {
        // ---------- GEMM1: h frags for f-strip [fc*64+fs*32, +32) x 32 toks
        f32x16 hA, hB;
#pragma unroll
        for (int r = 0; r < 16; ++r) { hA[r] = 0.f; hB[r] = 0.f; }

        const short* w1p = w1e + ((size_t)(fc * 2 + fs) * 16) * 512 + lane * 8;
        bf16x8 afr[8];
#pragma unroll
        for (int k = 0; k < 8; ++k) afr[k] = *(const bf16x8*)(w1p + k * 512);
#pragma unroll
        for (int k = 0; k < 8; ++k) {
            if ((k & 1) == 0) hA = __builtin_amdgcn_mfma_f32_32x32x16_bf16(afr[k], xr[k], hA, 0, 0, 0);
            else              hB = __builtin_amdgcn_mfma_f32_32x32x16_bf16(afr[k], xr[k], hB, 0, 0, 0);
            afr[k] = *(const bf16x8*)(w1p + (k + 8) * 512);
        }
#pragma unroll
        for (int k = 0; k < 8; ++k) {
            if ((k & 1) == 0) hA = __builtin_amdgcn_mfma_f32_32x32x16_bf16(afr[k], xr[k + 8], hA, 0, 0, 0);
            else              hB = __builtin_amdgcn_mfma_f32_32x32x16_bf16(afr[k], xr[k + 8], hB, 0, 0, 0);
        }

        // ---------- bias + relu + pack -> hs[buf] (frag-major, b64 writes)
        {
            short* hb = &hs[fc & 1][0];
#pragma unroll
            for (int q = 0; q < 4; ++q) {            // r0 = 4q
                const int r0  = q * 4;
                const int fl0 = 8 * q + 4 * g;       // f-local in [0,32)
                float4 bq = *(const float4*)(b1e + fc * 64 + fs * 32 + fl0);
                float h0 = fmaxf(hA[r0]     + hB[r0]     + bq.x, 0.f);
                float h1 = fmaxf(hA[r0 + 1] + hB[r0 + 1] + bq.y, 0.f);
                float h2 = fmaxf(hA[r0 + 2] + hB[r0 + 2] + bq.z, 0.f);
                float h3 = fmaxf(hA[r0 + 3] + hB[r0 + 3] + bq.w, 0.f);
                uint2 pk;
                pk.x = (unsigned)f2bf(h0) | ((unsigned)f2bf(h1) << 16);
                pk.y = (unsigned)f2bf(h2) | ((unsigned)f2bf(h3) << 16);
                const int frag = (2 * fs + (q >> 1)) * 4 + tg;
                const int boff = frag * 1024 + ((q & 1) ? 512 : 0) + l31 * 16 + 8 * g;
                *(uint2*)((char*)hb + boff) = pk;
            }
        }

        // ---------- issue w2 frags for this fchunk BEFORE the barrier
        bf16x8 wb[4][2];
        {
            const short* w2p = w2e + lane * 8;
#pragma unroll
            for (int fb = 0; fb < 4; ++fb)
#pragma unroll
                for (int cb = 0; cb < 2; ++cb)
                    wb[fb][cb] = *(const bf16x8*)(w2p +
                        ((size_t)((cg * 2 + cb) * 64 + fc * 4 + fb)) * 512);
        }
        __syncthreads();

        // ---------- GEMM2: acc += h @ w2 over this fchunk's 64 f
        {
            const short* hb = &hs[fc & 1][0];
            bf16x8 ha[4][2];
#pragma unroll
            for (int fb = 0; fb < 4; ++fb)
#pragma unroll
                for (int tp = 0; tp < 2; ++tp)
                    ha[fb][tp] = *(const bf16x8*)(hb + (fb * 4 + tg2 * 2 + tp) * 512 + lane * 8);
#pragma unroll
            for (int fb = 0; fb < 4; ++fb)
#pragma unroll
                for (int tp = 0; tp < 2; ++tp)
#pragma unroll
                    for (int cb = 0; cb < 2; ++cb)
                        acc[tp][cb] = __builtin_amdgcn_mfma_f32_32x32x16_bf16(
                            ha[fb][tp], wb[fb][cb], acc[tp][cb], 0, 0, 0);
        }
    }

    // ---- epilogue: out[tok] += p*(acc + b2); exactly 2 commutative fp32
    // atomics per output element from a zeroed buffer -> deterministic.
    const float* b2e = b2 + e * D;
#pragma unroll
    for (int tp = 0; tp < 2; ++tp) {
#pragma unroll
        for (int cb = 0; cb < 2; ++cb) {
            const int col = cg * 64 + cb * 32 + l31;
            const float bv = b2e[col];
#pragma unroll
            for (int r = 0; r < 16; ++r) {
                const int tl = (tg2 * 2 + tp) * 32 + (r & 3) + 8 * (r >> 2) + 4 * g;
                const int tk = tok_s[tl];
                if (tk >= 0)
                    atomicAdd(out + (size_t)tk * D + col,
                              (acc[tp][cb][r] + bv) * p_s[tl]);
            }
        }
    }
}

// ---------------------------------------------------------------------------
extern "C" void kernel_launch(void* const* d_in, const int* in_sizes, int n_in,
                              void* d_out, int out_size, void* d_ws, size_t ws_size,
                              hipStream_t stream) {
    const float* x  = (const float*)d_in[0];
    const float* gw = (const float*)d_in[1];
    const float* gb = (const float*)d_in[2];
    const float* w1 = (const float*)d_in[3];
    const float* b1 = (const float*)d_in[4];
    const float* w2 = (const float*)d_in[5];
    const float* b2 = (const float*)d_in[6];
    float* out = (float*)d_out;

    // ws: cnt 256B | bidx 1MB | bp 1MB | w1f 4MB | w2f 4MB.
    // Gate temporaries (epair/probs/hists/bases) alias the w1f region:
    // consumed by gate_scatter BEFORE w1f_prep runs (stream-ordered).
    char* ws = (char*)d_ws;
    int*   cnt   = (int*)ws;
    int*   bidx  = (int*)(ws + 256);
    float* bp    = (float*)(ws + 256 + (size_t)NE * N_TOK * 4);
    short* w1f   = (short*)(ws + 256 + (size_t)NE * N_TOK * 8);
    short* w2f   = w1f + (size_t)NE * D * DFF;

    unsigned* epair = (unsigned*)w1f;                       // 128KB
    float*    probs = (float*)((char*)w1f + (128 << 10));   // 256KB
    int*      hists = (int*)((char*)w1f + (384 << 10));     // 8KB
    int*      bases = (int*)((char*)w1f + (392 << 10));     // 8KB

    hipMemsetAsync(d_out, 0, (size_t)out_size * sizeof(float), stream);

    gate_compute<<<N_TOK / 128, 128, 0, stream>>>(x, gw, gb, epair, probs, hists);
    gate_scan<<<1, 256, 0, stream>>>(hists, bases, cnt);
    gate_scatter<<<N_TOK / 128, 128, 0, stream>>>(epair, probs, bases, bidx, bp);
    w1f_prep<<<1024, 256, 0, stream>>>(w1, w1f);
    w2f_prep<<<1024, 256, 0, stream>>>(w2, w2f);
    expert_ffn<<<NE * (N_TOK / TB), 512, 0, stream>>>(x, w1f, w2f, b1, b2,
                                                      cnt, bidx, bp, out);
}

// Round 5
// 199.170 us; speedup vs baseline: 1.4359x; 1.4359x over previous
//
#include <hip/hip_runtime.h>

#define N_TOK 32768
#define D 256
#define DFF 1024
#define NE 8
#define TB 64    // tokens per expert_ffn block

typedef __attribute__((ext_vector_type(16))) float f32x16;
typedef __attribute__((ext_vector_type(8)))  short bf16x8;

// fp32 -> bf16 round-to-nearest-even
__device__ __forceinline__ unsigned short f2bf(float f) {
    union { float f; unsigned u; } v; v.f = f;
    unsigned r = v.u + 0x7FFFu + ((v.u >> 16) & 1u);
    return (unsigned short)(r >> 16);
}

// ===========================================================================
// Prepass: w1 [E][D=256 d][DFF=1024 f] fp32 -> frag-major bf16 (GEMM1-A).
// frag = (e*32+fblk)*16 + dblk; element (lane l, j): f = fblk*32 + (l&31),
// d = dblk*16 + (l>>5)*8 + j.  (verified rounds 2-4)
// ===========================================================================
__global__ __launch_bounds__(256) void w1f_prep(
    const float* __restrict__ w1, short* __restrict__ w1f) {
    const int gid  = blockIdx.x * 256 + threadIdx.x;
    const int lane = gid & 63;
    const int frag = gid >> 6;
    const int dblk = frag & 15;
    const int fblk = (frag >> 4) & 31;
    const int e    = frag >> 9;
    const int l31 = lane & 31, g = lane >> 5;

    const float* src = w1 + ((size_t)e * 256 + dblk * 16 + g * 8) * 1024
                          + fblk * 32 + l31;
    unsigned u[4];
#pragma unroll
    for (int jp = 0; jp < 4; ++jp) {
        float a = src[(size_t)(jp * 2)     * 1024];
        float b = src[(size_t)(jp * 2 + 1) * 1024];
        u[jp] = (unsigned)f2bf(a) | ((unsigned)f2bf(b) << 16);
    }
    *(uint4*)(w1f + (size_t)gid * 8) = make_uint4(u[0], u[1], u[2], u[3]);
}

// ===========================================================================
// Prepass: w2 [E][DFF f][D col] fp32 -> frag-major bf16 (GEMM2-B).
// frag = (e*8+cblk)*64 + fblk; element: col = cblk*32 + (l&31),
// f = fblk*16 + (l>>5)*8 + j.  (verified rounds 2-4)
// ===========================================================================
__global__ __launch_bounds__(256) void w2f_prep(
    const float* __restrict__ w2, short* __restrict__ w2f) {
    const int gid  = blockIdx.x * 256 + threadIdx.x;
    const int lane = gid & 63;
    const int frag = gid >> 6;
    const int fblk = frag & 63;
    const int cblk = (frag >> 6) & 7;
    const int e    = frag >> 9;
    const int l31 = lane & 31, g = lane >> 5;

    const float* src = w2 + ((size_t)e * 1024 + fblk * 16 + g * 8) * 256
                          + cblk * 32 + l31;
    unsigned u[4];
#pragma unroll
    for (int jp = 0; jp < 4; ++jp) {
        float a = src[(size_t)(jp * 2)     * 256];
        float b = src[(size_t)(jp * 2 + 1) * 256];
        u[jp] = (unsigned)f2bf(a) | ((unsigned)f2bf(b) << 16);
    }
    *(uint4*)(w2f + (size_t)gid * 8) = make_uint4(u[0], u[1], u[2], u[3]);
}

// ===========================================================================
// Gate phase A: per-token fp64 logits + top-2 + softmax; per-block histogram.
// ===========================================================================
__global__ __launch_bounds__(128) void gate_compute(
    const float* __restrict__ x, const float* __restrict__ gw,
    const float* __restrict__ gb,
    unsigned* __restrict__ epair, float* __restrict__ probs,
    int* __restrict__ hists) {
    __shared__ float gws[2048];   // [d][e]
    __shared__ int   hist[NE];
    const int tid = threadIdx.x;
#pragma unroll
    for (int i = 0; i < 4; ++i)
        *(float4*)&gws[i * 512 + tid * 4] = *(const float4*)&gw[i * 512 + tid * 4];
    if (tid < NE) hist[tid] = 0;
    __syncthreads();

    const int t = blockIdx.x * 128 + tid;
    const float* xr = x + (size_t)t * D;

    double acc[NE];
#pragma unroll
    for (int e = 0; e < NE; ++e) acc[e] = 0.0;

    for (int d0 = 0; d0 < 256; d0 += 4) {
        float4 xv = *(const float4*)(xr + d0);
        float xa[4] = {xv.x, xv.y, xv.z, xv.w};
#pragma unroll
        for (int j = 0; j < 4; ++j) {
            float4 ga = *(const float4*)&gws[(d0 + j) * 8];
            float4 gbb = *(const float4*)&gws[(d0 + j) * 8 + 4];
            double xd = (double)xa[j];
            acc[0] += xd * (double)ga.x;  acc[1] += xd * (double)ga.y;
            acc[2] += xd * (double)ga.z;  acc[3] += xd * (double)ga.w;
            acc[4] += xd * (double)gbb.x; acc[5] += xd * (double)gbb.y;
            acc[6] += xd * (double)gbb.z; acc[7] += xd * (double)gbb.w;
        }
    }

    double l[NE];
#pragma unroll
    for (int e = 0; e < NE; ++e) l[e] = acc[e] + (double)gb[e];
    int e1 = 0;
#pragma unroll
    for (int e = 1; e < NE; ++e) if (l[e] > l[e1]) e1 = e;
    int e2 = (e1 == 0) ? 1 : 0;
#pragma unroll
    for (int e = 0; e < NE; ++e) if (e != e1 && l[e] > l[e2]) e2 = e;

    double s = 0.0;
#pragma unroll
    for (int e = 0; e < NE; ++e) s += exp(l[e] - l[e1]);

    atomicAdd(&hist[e1], 1);
    atomicAdd(&hist[e2], 1);
    epair[t] = (unsigned)e1 | ((unsigned)e2 << 8);
    probs[2 * t]     = (float)(1.0 / s);
    probs[2 * t + 1] = (float)(exp(l[e2] - l[e1]) / s);
    __syncthreads();
    if (tid < NE) hists[blockIdx.x * NE + tid] = hist[tid];
}

// ===========================================================================
// Gate phase B: exclusive prefix scan of per-block histograms.
// ===========================================================================
__global__ __launch_bounds__(256) void gate_scan(
    const int* __restrict__ hists, int* __restrict__ bases, int* __restrict__ cnt) {
    __shared__ int s[256];
    const int tid = threadIdx.x;
    for (int e = 0; e < NE; ++e) {
        int v = hists[tid * NE + e];
        s[tid] = v;
        __syncthreads();
        for (int off = 1; off < 256; off <<= 1) {
            int t = (tid >= off) ? s[tid - off] : 0;
            __syncthreads();
            s[tid] += t;
            __syncthreads();
        }
        bases[tid * NE + e] = s[tid] - v;
        if (tid == 255) cnt[e] = s[255];
        __syncthreads();
    }
}

// ===========================================================================
// Gate phase C: scatter tokens into per-expert bins at reserved ranges.
// ===========================================================================
__global__ __launch_bounds__(128) void gate_scatter(
    const unsigned* __restrict__ epair, const float* __restrict__ probs,
    const int* __restrict__ bases,
    int* __restrict__ bidx, float* __restrict__ bp) {
    __shared__ int hist[NE], bs[NE];
    const int tid = threadIdx.x;
    if (tid < NE) { hist[tid] = 0; bs[tid] = bases[blockIdx.x * NE + tid]; }
    __syncthreads();
    const int t = blockIdx.x * 128 + tid;
    const unsigned u = epair[t];
    const int e1 = u & 255, e2 = (u >> 8) & 255;
    const float p1 = probs[2 * t], p2 = probs[2 * t + 1];
    const int pos1 = atomicAdd(&hist[e1], 1);
    const int pos2 = atomicAdd(&hist[e2], 1);
    const int o1 = e1 * N_TOK + bs[e1] + pos1;
    const int o2 = e2 * N_TOK + bs[e2] + pos2;
    bidx[o1] = t;  bp[o1] = p1;
    bidx[o2] = t;  bp[o2] = p2;
}

// ===========================================================================
// Expert FFN v5. Block = 64 tok x 256 out, 4 waves (256 thr), 3 blocks/CU.
// fchunk = 128 f, 8 iters, 2 barriers each. MFMA 32x32x16 (conv. verified).
//  - ZERO weight-load redundancy: GEMM1 wave fs=wid owns 32-f strip (16
//    unique w1 frags); GEMM2 wave cg=wid owns 64 cols (16 unique w2 frags).
//    -> 1 MB L2 per block, 1 GB total.
//  - xs frag-major LDS (32 KB, conflict-free b128 reads), hs frag-major
//    (16 KB, contiguous 512B writes / 1KB reads, conflict-free).
//  - Barrier 1 (post-GEMM1) separates prev GEMM2 hs reads from pack writes;
//    barrier 2 (post-pack) separates pack writes from GEMM2 reads.
//    fb=0 w2 pair prefetched above barrier 2; rest rolling.
//  - blockIdx&7 = expert -> per-XCD L2 weight affinity.
// ===========================================================================
__global__ __launch_bounds__(256, 3) void expert_ffn(
    const float* __restrict__ x,
    const short* __restrict__ w1f,
    const short* __restrict__ w2f,
    const float* __restrict__ b1, const float* __restrict__ b2,
    const int* __restrict__ cnt, const int* __restrict__ bidx,
    const float* __restrict__ bp, float* __restrict__ out) {
    const int e    = blockIdx.x & 7;
    const int tile = blockIdx.x >> 3;
    const int n_e  = cnt[e];
    const int row0 = tile * TB;
    if (row0 >= n_e) return;

    __shared__ short xs[16 * 64 * 16];   // 32KB [dblk][tok][16] frag-major
    __shared__ short hs[16 * 512];       // 16KB [frag(fb*2+tp)][512]
    __shared__ int   tok_s[TB];
    __shared__ float p_s[TB];

    const int tid  = threadIdx.x;
    const int lane = tid & 63, wid = tid >> 6;
    const int l31  = lane & 31, g = lane >> 5;

    if (tid < TB) {
        int r = row0 + tid;
        tok_s[tid] = (r < n_e) ? bidx[e * N_TOK + r] : -1;
        p_s[tid]   = (r < n_e) ? bp[e * N_TOK + r] : 0.f;
    }
    __syncthreads();

    // ---- stage x -> xs (bf16 frag-major): element (tok, d=db*16+g*8+j)
    // at xs[db*1024 + tok*16 + g*8 + j]. Invalid rows zero-filled.
    {
        const int tok = tid >> 2;
        const int tk  = tok_s[tok];
        const float* xrow = x + (size_t)(tk < 0 ? 0 : tk) * D;
#pragma unroll
        for (int i = 0; i < 4; ++i) {
            const int dblk = (tid & 3) * 4 + i;
            unsigned u[8];
            if (tk >= 0) {
#pragma unroll
                for (int q = 0; q < 4; ++q) {
                    float4 v = *(const float4*)(xrow + dblk * 16 + q * 4);
                    u[q * 2 + 0] = (unsigned)f2bf(v.x) | ((unsigned)f2bf(v.y) << 16);
                    u[q * 2 + 1] = (unsigned)f2bf(v.z) | ((unsigned)f2bf(v.w) << 16);
                }
            } else {
#pragma unroll
                for (int q = 0; q < 8; ++q) u[q] = 0;
            }
            short* dp = &xs[dblk * 1024 + tok * 16];
            *(uint4*)(dp)     = make_uint4(u[0], u[1], u[2], u[3]);
            *(uint4*)(dp + 8) = make_uint4(u[4], u[5], u[6], u[7]);
        }
    }

    f32x16 acc[2][2];   // [tp tok-half][cb col-half]
#pragma unroll
    for (int a = 0; a < 2; ++a)
#pragma unroll
        for (int b = 0; b < 2; ++b)
#pragma unroll
            for (int r = 0; r < 16; ++r) acc[a][b][r] = 0.f;

    const short* w1e = w1f + (size_t)e * (32 * 16 * 512);
    const short* w2e = w2f + (size_t)e * (8 * 64 * 512);
    const float* b1e = b1 + e * DFF;

    __syncthreads();   // xs ready

    for (int fc = 0; fc < 8; ++fc) {
        // ---------- GEMM1: wave wid -> f-strip [fc*128+wid*32, +32) x 64 tok
        f32x16 h0, h1;
#pragma unroll
        for (int r = 0; r < 16; ++r) { h0[r] = 0.f; h1[r] = 0.f; }

        const short* w1p = w1e + ((size_t)(fc * 4 + wid) * 16) * 512 + lane * 8;
        {
            bf16x8 a0 = *(const bf16x8*)(w1p);
            bf16x8 x0 = *(const bf16x8*)&xs[l31 * 16 + g * 8];
            bf16x8 x1 = *(const bf16x8*)&xs[512 + l31 * 16 + g * 8];
#pragma unroll
            for (int db = 0; db < 16; ++db) {
                bf16x8 an, y0, y1;
                if (db < 15) {
                    an = *(const bf16x8*)(w1p + (db + 1) * 512);
                    y0 = *(const bf16x8*)&xs[(db + 1) * 1024 + l31 * 16 + g * 8];
                    y1 = *(const bf16x8*)&xs[(db + 1) * 1024 + 512 + l31 * 16 + g * 8];
                }
                h0 = __builtin_amdgcn_mfma_f32_32x32x16_bf16(a0, x0, h0, 0, 0, 0);
                h1 = __builtin_amdgcn_mfma_f32_32x32x16_bf16(a0, x1, h1, 0, 0, 0);
                if (db < 15) { a0 = an; x0 = y0; x1 = y1; }
            }
        }

        __syncthreads();   // prev GEMM2 hs reads done (all waves past GEMM1)

        // ---------- pack: bias+relu+bf16 -> hs frag-major.
        // hacc[th][r=4m+a] is h(tok = th*32+l31, f_loc = wid*32 + 8m+4g+a).
        // hs element (tok, f128): frag = (f128>>4)*2 + tp, lane' = (tok&31)
        //   + 32*((f128>>3)&1), slot = f128&7.
#pragma unroll
        for (int th = 0; th < 2; ++th) {
            const f32x16& hh = th ? h1 : h0;
#pragma unroll
            for (int m = 0; m < 4; ++m) {
                float4 bq = *(const float4*)(b1e + fc * 128 + wid * 32 + 8 * m + 4 * g);
                float v0 = fmaxf(hh[4 * m + 0] + bq.x, 0.f);
                float v1 = fmaxf(hh[4 * m + 1] + bq.y, 0.f);
                float v2 = fmaxf(hh[4 * m + 2] + bq.z, 0.f);
                float v3 = fmaxf(hh[4 * m + 3] + bq.w, 0.f);
                uint2 pk;
                pk.x = (unsigned)f2bf(v0) | ((unsigned)f2bf(v1) << 16);
                pk.y = (unsigned)f2bf(v2) | ((unsigned)f2bf(v3) << 16);
                const int fragid = (2 * wid + (m >> 1)) * 2 + th;
                *(uint2*)&hs[fragid * 512 + ((m & 1) * 32 + l31) * 8 + 4 * g] = pk;
            }
        }

        // ---------- prefetch fb=0 w2 pair above the barrier
        const short* w2p = w2e + ((size_t)(wid * 2) * 64 + fc * 8) * 512 + lane * 8;
        bf16x8 wb0a = *(const bf16x8*)(w2p);
        bf16x8 wb0b = *(const bf16x8*)(w2p + (size_t)64 * 512);

        __syncthreads();   // hs ready

        // ---------- GEMM2: wave wid -> cols [wid*64, +64), k over 128 f
#pragma unroll
        for (int fb = 0; fb < 8; ++fb) {
            bf16x8 ha0 = *(const bf16x8*)&hs[(fb * 2 + 0) * 512 + lane * 8];
            bf16x8 ha1 = *(const bf16x8*)&hs[(fb * 2 + 1) * 512 + lane * 8];
            bf16x8 wna, wnb;
            if (fb < 7) {
                wna = *(const bf16x8*)(w2p + (fb + 1) * 512);
                wnb = *(const bf16x8*)(w2p + (fb + 1) * 512 + (size_t)64 * 512);
            }
            acc[0][0] = __builtin_amdgcn_mfma_f32_32x32x16_bf16(ha0, wb0a, acc[0][0], 0, 0, 0);
            acc[0][1] = __builtin_amdgcn_mfma_f32_32x32x16_bf16(ha0, wb0b, acc[0][1], 0, 0, 0);
            acc[1][0] = __builtin_amdgcn_mfma_f32_32x32x16_bf16(ha1, wb0a, acc[1][0], 0, 0, 0);
            acc[1][1] = __builtin_amdgcn_mfma_f32_32x32x16_bf16(ha1, wb0b, acc[1][1], 0, 0, 0);
            if (fb < 7) { wb0a = wna; wb0b = wnb; }
        }
    }

    // ---- epilogue: out[tok] += p*(acc + b2); exactly 2 commutative fp32
    // atomics per output element from a zeroed buffer -> deterministic.
    const float* b2e = b2 + e * D;
#pragma unroll
    for (int tp = 0; tp < 2; ++tp) {
#pragma unroll
        for (int cb = 0; cb < 2; ++cb) {
            const int col = wid * 64 + cb * 32 + l31;
            const float bv = b2e[col];
#pragma unroll
            for (int r = 0; r < 16; ++r) {
                const int tl = tp * 32 + (r & 3) + 8 * (r >> 2) + 4 * g;
                const int tk = tok_s[tl];
                if (tk >= 0)
                    atomicAdd(out + (size_t)tk * D + col,
                              (acc[tp][cb][r] + bv) * p_s[tl]);
            }
        }
    }
}

// ---------------------------------------------------------------------------
extern "C" void kernel_launch(void* const* d_in, const int* in_sizes, int n_in,
                              void* d_out, int out_size, void* d_ws, size_t ws_size,
                              hipStream_t stream) {
    const float* x  = (const float*)d_in[0];
    const float* gw = (const float*)d_in[1];
    const float* gb = (const float*)d_in[2];
    const float* w1 = (const float*)d_in[3];
    const float* b1 = (const float*)d_in[4];
    const float* w2 = (const float*)d_in[5];
    const float* b2 = (const float*)d_in[6];
    float* out = (float*)d_out;

    // ws: cnt 256B | bidx 1MB | bp 1MB | w1f 4MB | w2f 4MB.
    // Gate temporaries alias w1f (consumed before w1f_prep; stream-ordered).
    char* ws = (char*)d_ws;
    int*   cnt   = (int*)ws;
    int*   bidx  = (int*)(ws + 256);
    float* bp    = (float*)(ws + 256 + (size_t)NE * N_TOK * 4);
    short* w1f   = (short*)(ws + 256 + (size_t)NE * N_TOK * 8);
    short* w2f   = w1f + (size_t)NE * D * DFF;

    unsigned* epair = (unsigned*)w1f;                       // 128KB
    float*    probs = (float*)((char*)w1f + (128 << 10));   // 256KB
    int*      hists = (int*)((char*)w1f + (384 << 10));     // 8KB
    int*      bases = (int*)((char*)w1f + (392 << 10));     // 8KB

    hipMemsetAsync(d_out, 0, (size_t)out_size * sizeof(float), stream);

    gate_compute<<<N_TOK / 128, 128, 0, stream>>>(x, gw, gb, epair, probs, hists);
    gate_scan<<<1, 256, 0, stream>>>(hists, bases, cnt);
    gate_scatter<<<N_TOK / 128, 128, 0, stream>>>(epair, probs, bases, bidx, bp);
    w1f_prep<<<1024, 256, 0, stream>>>(w1, w1f);
    w2f_prep<<<1024, 256, 0, stream>>>(w2, w2f);
    expert_ffn<<<NE * (N_TOK / TB), 256, 0, stream>>>(x, w1f, w2f, b1, b2,
                                                      cnt, bidx, bp, out);
}